// Round 17
// baseline (28.123 us; speedup 1.0000x reference)
//
#include <hip/hip_runtime.h>
#include <math.h>

#define N_PTS 16384
#define WAVE_P 128                 // p-cols per wave (4 B-frags x 32)
#define BLK_P  512                 // p per block (4 waves)
#define NPB    (N_PTS / BLK_P)     // 32
#define CHUNK_G 512                // g per chunk
#define NCH    (N_PTS / CHUNK_G)   // 32
#define NGROUP (CHUNK_G / 32)      // 16 A-groups per chunk

typedef __attribute__((ext_vector_type(8)))  short short8_t;
typedef __attribute__((ext_vector_type(16))) float f32x16;

// --- bf16 helpers (round-to-nearest-even) ---
__device__ __forceinline__ unsigned short bf_rn(float x) {
    unsigned u = __float_as_uint(x);
    unsigned r = (u + 0x7fffu + ((u >> 16) & 1u)) >> 16;
    return (unsigned short)r;
}
__device__ __forceinline__ float bf_up(unsigned short s) {
    return __uint_as_float(((unsigned)s) << 16);
}
// Monotone float->u32 encoding: unsigned min == float min (finite values).
__device__ __forceinline__ unsigned enc_f32(float f) {
    unsigned b = __float_as_uint(f);
    return (b & 0x80000000u) ? ~b : (b | 0x80000000u);
}
__device__ __forceinline__ float dec_f32(unsigned k) {
    unsigned b = (k & 0x80000000u) ? (k & 0x7fffffffu) : ~k;
    return __uint_as_float(b);
}
__device__ __forceinline__ float min3f(float a, float b, float c) {
    return fminf(fminf(a, b), c);      // -> v_min3_f32
}

// Prep: pws/gws (fallback path), pp[], bf16-split MFMA rows paA (g) / pbB (p),
// keys = +inf.
__global__ __launch_bounds__(256) void k_prep(
        const float* __restrict__ R, const float* __restrict__ t,
        const float* __restrict__ m, const float* __restrict__ g,
        float4* __restrict__ pws, float4* __restrict__ gws,
        float* __restrict__ ppv,
        unsigned short* __restrict__ paA, unsigned short* __restrict__ pbB,
        unsigned* __restrict__ keys) {
    int n = blockIdx.x * 256 + threadIdx.x;
    keys[n] = 0xFFFFFFFFu;

    float mx = m[3*n+0], my = m[3*n+1], mz = m[3*n+2];
    float px = fmaf(R[0], mx, fmaf(R[1], my, R[2]*mz)) + t[0];
    float py = fmaf(R[3], mx, fmaf(R[4], my, R[5]*mz)) + t[1];
    float pz = fmaf(R[6], mx, fmaf(R[7], my, R[8]*mz)) + t[2];
    float pp = fmaf(px,px,fmaf(py,py,pz*pz));
    pws[n] = make_float4(-2.f*px, -2.f*py, -2.f*pz, pp);
    ppv[n] = pp;
    float gx = g[3*n+0], gy = g[3*n+1], gz = g[3*n+2];
    float gg = fmaf(gx,gx,fmaf(gy,gy,gz*gz));
    gws[n] = make_float4(gx, gy, gz, gg);

    float Px = -2.f*px, Py = -2.f*py, Pz = -2.f*pz;
    unsigned short phx = bf_rn(Px), phy = bf_rn(Py), phz = bf_rn(Pz);
    unsigned short plx = bf_rn(Px - bf_up(phx)),
                   ply = bf_rn(Py - bf_up(phy)),
                   plz = bf_rn(Pz - bf_up(phz));
    unsigned short ghx = bf_rn(gx), ghy = bf_rn(gy), ghz = bf_rn(gz);
    unsigned short glx = bf_rn(gx - bf_up(ghx)),
                   gly = bf_rn(gy - bf_up(ghy)),
                   glz = bf_rn(gz - bf_up(ghz));
    unsigned short ggh = bf_rn(gg), ggl = bf_rn(gg - bf_up(ggh));
    const unsigned short one = 0x3F80;

    union { unsigned short u[16]; int4 v[2]; } A, B;
    // A (g row): gh gh gh | gh gh gh | gg_h gg_l | gl gl gl | 0...
    A.u[0]=ghx; A.u[1]=ghy; A.u[2]=ghz; A.u[3]=ghx; A.u[4]=ghy; A.u[5]=ghz;
    A.u[6]=ggh; A.u[7]=ggl; A.u[8]=glx; A.u[9]=gly; A.u[10]=glz;
    A.u[11]=0; A.u[12]=0; A.u[13]=0; A.u[14]=0; A.u[15]=0;
    // B (p col): ph ph ph | pl pl pl | 1 1 | ph ph ph | 0...
    B.u[0]=phx; B.u[1]=phy; B.u[2]=phz; B.u[3]=plx; B.u[4]=ply; B.u[5]=plz;
    B.u[6]=one; B.u[7]=one; B.u[8]=phx; B.u[9]=phy; B.u[10]=phz;
    B.u[11]=0; B.u[12]=0; B.u[13]=0; B.u[14]=0; B.u[15]=0;

    int4* pa = (int4*)(paA + (size_t)n * 16);
    int4* pb = (int4*)(pbB + (size_t)n * 16);
    pa[0] = A.v[0]; pa[1] = A.v[1];
    pb[0] = B.v[0]; pb[1] = B.v[1];
}

// 16-value + carry min via v_min3 chains: 9 ops.
__device__ __forceinline__ float tree16c(f32x16 d, float carry) {
    float m0 = min3f(d[0],  d[1],  d[2]);
    float m1 = min3f(d[3],  d[4],  d[5]);
    float m2 = min3f(d[6],  d[7],  d[8]);
    float m3 = min3f(d[9],  d[10], d[11]);
    float m4 = min3f(d[12], d[13], d[14]);
    float m5 = min3f(m4, d[15], carry);
    return min3f(m0, m1, min3f(m2, m3, m5));
}

// MFMA NN — inline-asm VGPR MFMA with explicit hazard guard (2x s_nop 7:
// compiler doesn't insert MFMA->VALU wait states for asm-defined regs;
// r15 failed intermittently without them, r16 verified correct).
__global__ __launch_bounds__(256) void k_nn_mfma(
        const unsigned short* __restrict__ paA,
        const unsigned short* __restrict__ pbB,
        unsigned* __restrict__ keys) {
    const int tid = threadIdx.x;
    const int wid = tid >> 6, l = tid & 63;
    const int lc = l & 31, lh = l >> 5;
    const int pbase = blockIdx.x * BLK_P + wid * WAVE_P;
    const int g0 = blockIdx.y * CHUNK_G;

    short8_t B0 = *(const short8_t*)(pbB + (size_t)(pbase +  0 + lc)*16 + lh*8);
    short8_t B1 = *(const short8_t*)(pbB + (size_t)(pbase + 32 + lc)*16 + lh*8);
    short8_t B2 = *(const short8_t*)(pbB + (size_t)(pbase + 64 + lc)*16 + lh*8);
    short8_t B3 = *(const short8_t*)(pbB + (size_t)(pbase + 96 + lc)*16 + lh*8);

    const f32x16 zc = {};              // zero C operand, held in VGPRs
    float rm0 = 3.4e38f, rm1 = 3.4e38f, rm2 = 3.4e38f, rm3 = 3.4e38f;

    const unsigned short* aptr = paA + (size_t)(g0 + lc)*16 + lh*8;
    short8_t a = *(const short8_t*)aptr;

    #pragma unroll 2
    for (int gi = 0; gi < NGROUP; ++gi) {
        short8_t an = (gi + 1 < NGROUP)
                      ? *(const short8_t*)(aptr + (size_t)(gi + 1) * 512) : a;
        f32x16 d0, d1, d2, d3;
        asm("v_mfma_f32_32x32x16_bf16 %0, %4, %5, %9\n\t"
            "v_mfma_f32_32x32x16_bf16 %1, %4, %6, %9\n\t"
            "v_mfma_f32_32x32x16_bf16 %2, %4, %7, %9\n\t"
            "v_mfma_f32_32x32x16_bf16 %3, %4, %8, %9\n\t"
            "s_nop 7\n\t"
            "s_nop 7"
            : "=&v"(d0), "=&v"(d1), "=&v"(d2), "=&v"(d3)
            : "v"(a), "v"(B0), "v"(B1), "v"(B2), "v"(B3), "v"(zc));
        rm0 = tree16c(d0, rm0);
        rm1 = tree16c(d1, rm1);
        rm2 = tree16c(d2, rm2);
        rm3 = tree16c(d3, rm3);
        a = an;
    }

    // merge row-halves (lanes l and l^32: same column, disjoint g-rows)
    rm0 = fminf(rm0, __shfl_xor(rm0, 32, 64));
    rm1 = fminf(rm1, __shfl_xor(rm1, 32, 64));
    rm2 = fminf(rm2, __shfl_xor(rm2, 32, 64));
    rm3 = fminf(rm3, __shfl_xor(rm3, 32, 64));

    if (lh == 0) {
        atomicMin(&keys[pbase + lc],      enc_f32(rm0));
        atomicMin(&keys[pbase + 32 + lc], enc_f32(rm1));
        atomicMin(&keys[pbase + 64 + lc], enc_f32(rm2));
        atomicMin(&keys[pbase + 96 + lc], enc_f32(rm3));
    }
}

// Vector fallback (atomic keys) for small ws.
__global__ __launch_bounds__(256, 4) void k_nn_vec(
        const float4* __restrict__ pws, const float4* __restrict__ gws,
        unsigned* __restrict__ keys) {
    const int tid = threadIdx.x;
    const int pbase = blockIdx.x * 2048;
    const int g0 = blockIdx.y * 64;
    float px[8], py[8], pz[8], sm[8];
    #pragma unroll
    for (int k = 0; k < 8; ++k) {
        float4 p = pws[pbase + k*256 + tid];
        px[k]=p.x; py[k]=p.y; pz[k]=p.z; sm[k]=3.4e38f;
    }
    #pragma unroll 4
    for (int gi = 0; gi < 64; gi += 2) {
        float4 a = gws[g0 + gi];
        float4 b = gws[g0 + gi + 1];
        #pragma unroll
        for (int k = 0; k < 8; ++k) {
            float sa = fmaf(px[k], a.x, fmaf(py[k], a.y, fmaf(pz[k], a.z, a.w)));
            float sb = fmaf(px[k], b.x, fmaf(py[k], b.y, fmaf(pz[k], b.z, b.w)));
            sm[k] = fminf(sm[k], fminf(sa, sb));
        }
    }
    #pragma unroll
    for (int k = 0; k < 8; ++k)
        atomicMin(&keys[pbase + k*256 + tid], enc_f32(sm[k]));
}

// Fused finalize: ONE block, 1024 threads, 16 points each. dis = sqrt(max(
// pp + dec(key), 0)) (sym) or direct diff; fixed-order block reduction;
// thread 0 writes the mean. Replaces k_fin + k_final (one fewer graph node).
__global__ __launch_bounds__(1024) void k_fin1(
        const float* __restrict__ R, const float* __restrict__ t,
        const float* __restrict__ m, const float* __restrict__ g,
        const float* __restrict__ ppv, const unsigned* __restrict__ keys,
        const int* __restrict__ midx, float* __restrict__ out) {
    const int tid = threadIdx.x;
    const bool sym = (midx[0] == 0);
    float acc = 0.f;
    #pragma unroll
    for (int k = 0; k < N_PTS / 1024; ++k) {
        int n = k * 1024 + tid;                  // coalesced
        float dis;
        if (sym) {
            float d2 = ppv[n] + dec_f32(keys[n]);
            dis = sqrtf(fmaxf(d2, 0.f));
        } else {
            float mx=m[3*n+0], my=m[3*n+1], mz=m[3*n+2];
            float dx = fmaf(R[0],mx,fmaf(R[1],my,R[2]*mz)) + t[0] - g[3*n+0];
            float dy = fmaf(R[3],mx,fmaf(R[4],my,R[5]*mz)) + t[1] - g[3*n+1];
            float dz = fmaf(R[6],mx,fmaf(R[7],my,R[8]*mz)) + t[2] - g[3*n+2];
            dis = sqrtf(fmaf(dx,dx,fmaf(dy,dy,dz*dz)));
        }
        acc += dis;
    }
    #pragma unroll
    for (int off = 32; off > 0; off >>= 1) acc += __shfl_down(acc, off, 64);
    __shared__ float sred[16];
    if ((tid & 63) == 0) sred[tid >> 6] = acc;
    __syncthreads();
    if (tid == 0) {
        float v = 0.f;
        #pragma unroll
        for (int w = 0; w < 16; ++w) v += sred[w];   // fixed order
        out[0] = v / (float)N_PTS;
    }
}

extern "C" void kernel_launch(void* const* d_in, const int* in_sizes, int n_in,
                              void* d_out, int out_size, void* d_ws, size_t ws_size,
                              hipStream_t stream) {
    const float* R   = (const float*)d_in[0];
    const float* t   = (const float*)d_in[1];
    const float* m   = (const float*)d_in[2];
    const float* g   = (const float*)d_in[3];
    const int* midx  = (const int*)d_in[4];

    char* ws = (char*)d_ws;
    float* out = (float*)d_out;

    // layout: keys 64K | ppv 64K | pws 256K | gws 256K | paA 512K | pbB 512K
    unsigned* keys = (unsigned*)ws;
    float*    ppv  = (float*)(ws + 65536);
    float4*   pws  = (float4*)(ws + 65536 + 65536);
    float4*   gws  = (float4*)(ws + 65536 + 65536 + 262144);
    unsigned short* paA = (unsigned short*)(ws + 65536 + 65536 + 524288);
    unsigned short* pbB = paA + (size_t)16 * N_PTS;
    const size_t need = 65536 + 65536 + 524288 + 1048576;

    k_prep<<<dim3(N_PTS/256), dim3(256), 0, stream>>>(
        R, t, m, g, pws, gws, ppv, paA, pbB, keys);

    if (ws_size >= need) {
        k_nn_mfma<<<dim3(NPB, NCH), dim3(256), 0, stream>>>(paA, pbB, keys);
    } else {
        k_nn_vec<<<dim3(8, 256), dim3(256), 0, stream>>>(pws, gws, keys);
    }

    k_fin1<<<dim3(1), dim3(1024), 0, stream>>>(
        R, t, m, g, ppv, keys, midx, out);
}

// Round 18
// 24.803 us; speedup vs baseline: 1.1339x; 1.1339x over previous
//
#include <hip/hip_runtime.h>
#include <math.h>

#define N_PTS 16384
#define WAVE_P 128                 // p-cols per wave (4 B-frags x 32)
#define BLK_P  512                 // p per block (4 waves)
#define NPB    (N_PTS / BLK_P)     // 32
#define CHUNK_G 512                // g per chunk
#define NCH    (N_PTS / CHUNK_G)   // 32
#define NGROUP (CHUNK_G / 32)      // 16 A-groups per chunk
#define NFBLK  64                  // fin blocks (256 points each)

typedef __attribute__((ext_vector_type(8)))  short short8_t;
typedef __attribute__((ext_vector_type(16))) float f32x16;

// --- bf16 helpers (round-to-nearest-even) ---
__device__ __forceinline__ unsigned short bf_rn(float x) {
    unsigned u = __float_as_uint(x);
    unsigned r = (u + 0x7fffu + ((u >> 16) & 1u)) >> 16;
    return (unsigned short)r;
}
__device__ __forceinline__ float bf_up(unsigned short s) {
    return __uint_as_float(((unsigned)s) << 16);
}
// Monotone float->u32 encoding: unsigned min == float min (finite values).
__device__ __forceinline__ unsigned enc_f32(float f) {
    unsigned b = __float_as_uint(f);
    return (b & 0x80000000u) ? ~b : (b | 0x80000000u);
}
__device__ __forceinline__ float dec_f32(unsigned k) {
    unsigned b = (k & 0x80000000u) ? (k & 0x7fffffffu) : ~k;
    return __uint_as_float(b);
}
__device__ __forceinline__ float min3f(float a, float b, float c) {
    return fminf(fminf(a, b), c);      // -> v_min3_f32
}

// Prep: bf16-split MFMA rows paA (g) / pbB (p), pp[], keys=+inf.
// FALLBACK=true additionally writes pws/gws for the vector path.
template<bool FALLBACK>
__global__ __launch_bounds__(256) void k_prep(
        const float* __restrict__ R, const float* __restrict__ t,
        const float* __restrict__ m, const float* __restrict__ g,
        float4* __restrict__ pws, float4* __restrict__ gws,
        float* __restrict__ ppv,
        unsigned short* __restrict__ paA, unsigned short* __restrict__ pbB,
        unsigned* __restrict__ keys) {
    int n = blockIdx.x * 256 + threadIdx.x;
    keys[n] = 0xFFFFFFFFu;

    float mx = m[3*n+0], my = m[3*n+1], mz = m[3*n+2];
    float px = fmaf(R[0], mx, fmaf(R[1], my, R[2]*mz)) + t[0];
    float py = fmaf(R[3], mx, fmaf(R[4], my, R[5]*mz)) + t[1];
    float pz = fmaf(R[6], mx, fmaf(R[7], my, R[8]*mz)) + t[2];
    float pp = fmaf(px,px,fmaf(py,py,pz*pz));
    ppv[n] = pp;
    float gx = g[3*n+0], gy = g[3*n+1], gz = g[3*n+2];
    float gg = fmaf(gx,gx,fmaf(gy,gy,gz*gz));
    if (FALLBACK) {
        pws[n] = make_float4(-2.f*px, -2.f*py, -2.f*pz, pp);
        gws[n] = make_float4(gx, gy, gz, gg);
    }

    float Px = -2.f*px, Py = -2.f*py, Pz = -2.f*pz;
    unsigned short phx = bf_rn(Px), phy = bf_rn(Py), phz = bf_rn(Pz);
    unsigned short plx = bf_rn(Px - bf_up(phx)),
                   ply = bf_rn(Py - bf_up(phy)),
                   plz = bf_rn(Pz - bf_up(phz));
    unsigned short ghx = bf_rn(gx), ghy = bf_rn(gy), ghz = bf_rn(gz);
    unsigned short glx = bf_rn(gx - bf_up(ghx)),
                   gly = bf_rn(gy - bf_up(ghy)),
                   glz = bf_rn(gz - bf_up(ghz));
    unsigned short ggh = bf_rn(gg), ggl = bf_rn(gg - bf_up(ggh));
    const unsigned short one = 0x3F80;

    union { unsigned short u[16]; int4 v[2]; } A, B;
    // A (g row): gh gh gh | gh gh gh | gg_h gg_l | gl gl gl | 0...
    A.u[0]=ghx; A.u[1]=ghy; A.u[2]=ghz; A.u[3]=ghx; A.u[4]=ghy; A.u[5]=ghz;
    A.u[6]=ggh; A.u[7]=ggl; A.u[8]=glx; A.u[9]=gly; A.u[10]=glz;
    A.u[11]=0; A.u[12]=0; A.u[13]=0; A.u[14]=0; A.u[15]=0;
    // B (p col): ph ph ph | pl pl pl | 1 1 | ph ph ph | 0...
    B.u[0]=phx; B.u[1]=phy; B.u[2]=phz; B.u[3]=plx; B.u[4]=ply; B.u[5]=plz;
    B.u[6]=one; B.u[7]=one; B.u[8]=phx; B.u[9]=phy; B.u[10]=phz;
    B.u[11]=0; B.u[12]=0; B.u[13]=0; B.u[14]=0; B.u[15]=0;

    int4* pa = (int4*)(paA + (size_t)n * 16);
    int4* pb = (int4*)(pbB + (size_t)n * 16);
    pa[0] = A.v[0]; pa[1] = A.v[1];
    pb[0] = B.v[0]; pb[1] = B.v[1];
}

// 16-value + carry min via v_min3 chains: 9 ops.
__device__ __forceinline__ float tree16c(f32x16 d, float carry) {
    float m0 = min3f(d[0],  d[1],  d[2]);
    float m1 = min3f(d[3],  d[4],  d[5]);
    float m2 = min3f(d[6],  d[7],  d[8]);
    float m3 = min3f(d[9],  d[10], d[11]);
    float m4 = min3f(d[12], d[13], d[14]);
    float m5 = min3f(m4, d[15], carry);
    return min3f(m0, m1, min3f(m2, m3, m5));
}

// MFMA NN — inline-asm VGPR MFMA with explicit hazard guard (2x s_nop 7:
// compiler doesn't insert MFMA->VALU wait states for asm-defined regs;
// r15 failed intermittently without them, r16 verified correct).
__global__ __launch_bounds__(256) void k_nn_mfma(
        const unsigned short* __restrict__ paA,
        const unsigned short* __restrict__ pbB,
        unsigned* __restrict__ keys) {
    const int tid = threadIdx.x;
    const int wid = tid >> 6, l = tid & 63;
    const int lc = l & 31, lh = l >> 5;
    const int pbase = blockIdx.x * BLK_P + wid * WAVE_P;
    const int g0 = blockIdx.y * CHUNK_G;

    short8_t B0 = *(const short8_t*)(pbB + (size_t)(pbase +  0 + lc)*16 + lh*8);
    short8_t B1 = *(const short8_t*)(pbB + (size_t)(pbase + 32 + lc)*16 + lh*8);
    short8_t B2 = *(const short8_t*)(pbB + (size_t)(pbase + 64 + lc)*16 + lh*8);
    short8_t B3 = *(const short8_t*)(pbB + (size_t)(pbase + 96 + lc)*16 + lh*8);

    const f32x16 zc = {};              // zero C operand, held in VGPRs
    float rm0 = 3.4e38f, rm1 = 3.4e38f, rm2 = 3.4e38f, rm3 = 3.4e38f;

    const unsigned short* aptr = paA + (size_t)(g0 + lc)*16 + lh*8;
    short8_t a = *(const short8_t*)aptr;

    #pragma unroll 2
    for (int gi = 0; gi < NGROUP; ++gi) {
        short8_t an = (gi + 1 < NGROUP)
                      ? *(const short8_t*)(aptr + (size_t)(gi + 1) * 512) : a;
        f32x16 d0, d1, d2, d3;
        asm("v_mfma_f32_32x32x16_bf16 %0, %4, %5, %9\n\t"
            "v_mfma_f32_32x32x16_bf16 %1, %4, %6, %9\n\t"
            "v_mfma_f32_32x32x16_bf16 %2, %4, %7, %9\n\t"
            "v_mfma_f32_32x32x16_bf16 %3, %4, %8, %9\n\t"
            "s_nop 7\n\t"
            "s_nop 7"
            : "=&v"(d0), "=&v"(d1), "=&v"(d2), "=&v"(d3)
            : "v"(a), "v"(B0), "v"(B1), "v"(B2), "v"(B3), "v"(zc));
        rm0 = tree16c(d0, rm0);
        rm1 = tree16c(d1, rm1);
        rm2 = tree16c(d2, rm2);
        rm3 = tree16c(d3, rm3);
        a = an;
    }

    // merge row-halves (lanes l and l^32: same column, disjoint g-rows)
    rm0 = fminf(rm0, __shfl_xor(rm0, 32, 64));
    rm1 = fminf(rm1, __shfl_xor(rm1, 32, 64));
    rm2 = fminf(rm2, __shfl_xor(rm2, 32, 64));
    rm3 = fminf(rm3, __shfl_xor(rm3, 32, 64));

    if (lh == 0) {
        atomicMin(&keys[pbase + lc],      enc_f32(rm0));
        atomicMin(&keys[pbase + 32 + lc], enc_f32(rm1));
        atomicMin(&keys[pbase + 64 + lc], enc_f32(rm2));
        atomicMin(&keys[pbase + 96 + lc], enc_f32(rm3));
    }
}

// Vector fallback (atomic keys) for small ws.
__global__ __launch_bounds__(256, 4) void k_nn_vec(
        const float4* __restrict__ pws, const float4* __restrict__ gws,
        unsigned* __restrict__ keys) {
    const int tid = threadIdx.x;
    const int pbase = blockIdx.x * 2048;
    const int g0 = blockIdx.y * 64;
    float px[8], py[8], pz[8], sm[8];
    #pragma unroll
    for (int k = 0; k < 8; ++k) {
        float4 p = pws[pbase + k*256 + tid];
        px[k]=p.x; py[k]=p.y; pz[k]=p.z; sm[k]=3.4e38f;
    }
    #pragma unroll 4
    for (int gi = 0; gi < 64; gi += 2) {
        float4 a = gws[g0 + gi];
        float4 b = gws[g0 + gi + 1];
        #pragma unroll
        for (int k = 0; k < 8; ++k) {
            float sa = fmaf(px[k], a.x, fmaf(py[k], a.y, fmaf(pz[k], a.z, a.w)));
            float sb = fmaf(px[k], b.x, fmaf(py[k], b.y, fmaf(pz[k], b.z, b.w)));
            sm[k] = fminf(sm[k], fminf(sa, sb));
        }
    }
    #pragma unroll
    for (int k = 0; k < 8; ++k)
        atomicMin(&keys[pbase + k*256 + tid], enc_f32(sm[k]));
}

// Fin: dis = sqrt(max(pp + dec(key), 0)) (sym) or direct diff; block-reduce
// to psum[block]. No atomics, no fences.
__global__ __launch_bounds__(256) void k_fin(
        const float* __restrict__ R, const float* __restrict__ t,
        const float* __restrict__ m, const float* __restrict__ g,
        const float* __restrict__ ppv, const unsigned* __restrict__ keys,
        const int* __restrict__ midx, float* __restrict__ psum) {
    const int tid = threadIdx.x;
    const int n = blockIdx.x * 256 + tid;
    const bool sym = (midx[0] == 0);
    float dis;
    if (sym) {
        float d2 = ppv[n] + dec_f32(keys[n]);
        dis = sqrtf(fmaxf(d2, 0.f));
    } else {
        float mx=m[3*n+0], my=m[3*n+1], mz=m[3*n+2];
        float dx = fmaf(R[0],mx,fmaf(R[1],my,R[2]*mz)) + t[0] - g[3*n+0];
        float dy = fmaf(R[3],mx,fmaf(R[4],my,R[5]*mz)) + t[1] - g[3*n+1];
        float dz = fmaf(R[6],mx,fmaf(R[7],my,R[8]*mz)) + t[2] - g[3*n+2];
        dis = sqrtf(fmaf(dx,dx,fmaf(dy,dy,dz*dz)));
    }
    #pragma unroll
    for (int off = 32; off > 0; off >>= 1) dis += __shfl_down(dis, off, 64);
    __shared__ float sred[4];
    if ((tid & 63) == 0) sred[tid >> 6] = dis;
    __syncthreads();
    if (tid == 0) psum[blockIdx.x] = (sred[0] + sred[1]) + (sred[2] + sred[3]);
}

// Final: sum psum[NFBLK] -> mean.
__global__ void k_final(const float* __restrict__ psum, float* __restrict__ out) {
    float v = psum[threadIdx.x];
    #pragma unroll
    for (int off = 32; off > 0; off >>= 1) v += __shfl_down(v, off, 64);
    if (threadIdx.x == 0) out[0] = v / (float)N_PTS;
}

extern "C" void kernel_launch(void* const* d_in, const int* in_sizes, int n_in,
                              void* d_out, int out_size, void* d_ws, size_t ws_size,
                              hipStream_t stream) {
    const float* R   = (const float*)d_in[0];
    const float* t   = (const float*)d_in[1];
    const float* m   = (const float*)d_in[2];
    const float* g   = (const float*)d_in[3];
    const int* midx  = (const int*)d_in[4];

    char* ws = (char*)d_ws;
    float* out = (float*)d_out;

    // layout: keys 64K | psum 1K | ppv 64K | pws 256K | gws 256K | paA 512K | pbB 512K
    unsigned* keys = (unsigned*)ws;
    float*    psum = (float*)(ws + 65536);
    float*    ppv  = (float*)(ws + 65536 + 1024);
    float4*   pws  = (float4*)(ws + 65536 + 1024 + 65536);
    float4*   gws  = (float4*)(ws + 65536 + 1024 + 65536 + 262144);
    unsigned short* paA = (unsigned short*)(ws + 65536 + 1024 + 65536 + 524288);
    unsigned short* pbB = paA + (size_t)16 * N_PTS;
    const size_t need = 65536 + 1024 + 65536 + 524288 + 1048576;

    if (ws_size >= need) {
        k_prep<false><<<dim3(N_PTS/256), dim3(256), 0, stream>>>(
            R, t, m, g, pws, gws, ppv, paA, pbB, keys);
        k_nn_mfma<<<dim3(NPB, NCH), dim3(256), 0, stream>>>(paA, pbB, keys);
    } else {
        k_prep<true><<<dim3(N_PTS/256), dim3(256), 0, stream>>>(
            R, t, m, g, pws, gws, ppv, paA, pbB, keys);
        k_nn_vec<<<dim3(8, 256), dim3(256), 0, stream>>>(pws, gws, keys);
    }

    k_fin<<<dim3(NFBLK), dim3(256), 0, stream>>>(
        R, t, m, g, ppv, keys, midx, psum);
    k_final<<<dim3(1), dim3(64), 0, stream>>>(psum, out);
}

// Round 19
// 23.679 us; speedup vs baseline: 1.1877x; 1.0475x over previous
//
#include <hip/hip_runtime.h>
#include <math.h>

#define N_PTS 16384
#define WAVE_P 128                 // p-cols per wave (4 B-frags x 32)
#define BLK_P  512                 // p per block (4 waves)
#define NPB    (N_PTS / BLK_P)     // 32
#define CHUNK_G 512                // g per chunk
#define NCH    (N_PTS / CHUNK_G)   // 32
#define NGROUP (CHUNK_G / 32)      // 16 A-groups per chunk
#define NFBLK  64                  // fin blocks (256 points each)

typedef __attribute__((ext_vector_type(8)))  short short8_t;
typedef __attribute__((ext_vector_type(16))) float f32x16;

// --- bf16 helpers (round-to-nearest-even) ---
__device__ __forceinline__ unsigned short bf_rn(float x) {
    unsigned u = __float_as_uint(x);
    unsigned r = (u + 0x7fffu + ((u >> 16) & 1u)) >> 16;
    return (unsigned short)r;
}
__device__ __forceinline__ float bf_up(unsigned short s) {
    return __uint_as_float(((unsigned)s) << 16);
}
// Monotone float->u32 encoding: unsigned min == float min (finite values).
__device__ __forceinline__ unsigned enc_f32(float f) {
    unsigned b = __float_as_uint(f);
    return (b & 0x80000000u) ? ~b : (b | 0x80000000u);
}
__device__ __forceinline__ float dec_f32(unsigned k) {
    unsigned b = (k & 0x80000000u) ? (k & 0x7fffffffu) : ~k;
    return __uint_as_float(b);
}
__device__ __forceinline__ float min3f(float a, float b, float c) {
    return fminf(fminf(a, b), c);      // -> v_min3_f32
}
__device__ __forceinline__ short8_t pack8(unsigned short a0, unsigned short a1,
        unsigned short a2, unsigned short a3, unsigned short a4,
        unsigned short a5, unsigned short a6, unsigned short a7) {
    union { unsigned short u[8]; short8_t v; } x;
    x.u[0]=a0; x.u[1]=a1; x.u[2]=a2; x.u[3]=a3;
    x.u[4]=a4; x.u[5]=a5; x.u[6]=a6; x.u[7]=a7;
    return x.v;
}

// Prep: keys=+inf, ppv, g-side MFMA rows paA. FULL adds pws/gws (fallback).
template<bool FULL>
__global__ __launch_bounds__(256) void k_prep(
        const float* __restrict__ R, const float* __restrict__ t,
        const float* __restrict__ m, const float* __restrict__ g,
        float4* __restrict__ pws, float4* __restrict__ gws,
        float* __restrict__ ppv,
        unsigned short* __restrict__ paA,
        unsigned* __restrict__ keys) {
    int n = blockIdx.x * 256 + threadIdx.x;
    keys[n] = 0xFFFFFFFFu;

    float mx = m[3*n+0], my = m[3*n+1], mz = m[3*n+2];
    float px = fmaf(R[0], mx, fmaf(R[1], my, R[2]*mz)) + t[0];
    float py = fmaf(R[3], mx, fmaf(R[4], my, R[5]*mz)) + t[1];
    float pz = fmaf(R[6], mx, fmaf(R[7], my, R[8]*mz)) + t[2];
    float pp = fmaf(px,px,fmaf(py,py,pz*pz));
    ppv[n] = pp;
    float gx = g[3*n+0], gy = g[3*n+1], gz = g[3*n+2];
    float gg = fmaf(gx,gx,fmaf(gy,gy,gz*gz));
    if (FULL) {
        pws[n] = make_float4(-2.f*px, -2.f*py, -2.f*pz, pp);
        gws[n] = make_float4(gx, gy, gz, gg);
    }

    unsigned short ghx = bf_rn(gx), ghy = bf_rn(gy), ghz = bf_rn(gz);
    unsigned short glx = bf_rn(gx - bf_up(ghx)),
                   gly = bf_rn(gy - bf_up(ghy)),
                   glz = bf_rn(gz - bf_up(ghz));
    unsigned short ggh = bf_rn(gg), ggl = bf_rn(gg - bf_up(ggh));

    union { unsigned short u[16]; int4 v[2]; } A;
    // A (g row): gh gh gh | gh gh gh | gg_h gg_l | gl gl gl | 0...
    A.u[0]=ghx; A.u[1]=ghy; A.u[2]=ghz; A.u[3]=ghx; A.u[4]=ghy; A.u[5]=ghz;
    A.u[6]=ggh; A.u[7]=ggl; A.u[8]=glx; A.u[9]=gly; A.u[10]=glz;
    A.u[11]=0; A.u[12]=0; A.u[13]=0; A.u[14]=0; A.u[15]=0;

    int4* pa = (int4*)(paA + (size_t)n * 16);
    pa[0] = A.v[0]; pa[1] = A.v[1];
}

// 16-value + carry min via v_min3 chains: 9 ops.
__device__ __forceinline__ float tree16c(f32x16 d, float carry) {
    float m0 = min3f(d[0],  d[1],  d[2]);
    float m1 = min3f(d[3],  d[4],  d[5]);
    float m2 = min3f(d[6],  d[7],  d[8]);
    float m3 = min3f(d[9],  d[10], d[11]);
    float m4 = min3f(d[12], d[13], d[14]);
    float m5 = min3f(m4, d[15], carry);
    return min3f(m0, m1, min3f(m2, m3, m5));
}

// MFMA NN — B-frags built per-lane in registers (exact same fp ops as the
// old prep -> bit-identical bf16; kills pbB write+scattered reload).
// Inline-asm VGPR MFMA with s_nop hazard guard (r15/r16 lesson: the
// compiler doesn't insert MFMA->VALU wait states for asm-defined regs).
__global__ __launch_bounds__(256) void k_nn_mfma(
        const float* __restrict__ R, const float* __restrict__ t,
        const float* __restrict__ m,
        const unsigned short* __restrict__ paA,
        unsigned* __restrict__ keys) {
    const int tid = threadIdx.x;
    const int wid = tid >> 6, l = tid & 63;
    const int lc = l & 31, lh = l >> 5;
    const int pbase = blockIdx.x * BLK_P + wid * WAVE_P;
    const int g0 = blockIdx.y * CHUNK_G;

    const float r0=R[0], r1=R[1], r2=R[2], r3=R[3], r4=R[4],
                r5=R[5], r6=R[6], r7=R[7], r8=R[8];
    const float t0=t[0], t1=t[1], t2=t[2];

    // B frags per-lane: lane lc owns point pbase + f*32 + lc
    short8_t Bf[4];
    #pragma unroll
    for (int f = 0; f < 4; ++f) {
        int n = pbase + f * 32 + lc;
        float mx = m[3*n+0], my = m[3*n+1], mz = m[3*n+2];
        float px = fmaf(r0,mx,fmaf(r1,my,r2*mz)) + t0;
        float py = fmaf(r3,mx,fmaf(r4,my,r5*mz)) + t1;
        float pz = fmaf(r6,mx,fmaf(r7,my,r8*mz)) + t2;
        float Px = -2.f*px, Py = -2.f*py, Pz = -2.f*pz;
        unsigned short phx = bf_rn(Px), phy = bf_rn(Py), phz = bf_rn(Pz);
        if (lh == 0) {
            unsigned short plx = bf_rn(Px - bf_up(phx)),
                           ply = bf_rn(Py - bf_up(phy)),
                           plz = bf_rn(Pz - bf_up(phz));
            Bf[f] = pack8(phx, phy, phz, plx, ply, plz, 0x3F80, 0x3F80);
        } else {
            Bf[f] = pack8(phx, phy, phz, 0, 0, 0, 0, 0);
        }
    }

    const f32x16 zc = {};              // zero C operand, held in VGPRs
    float rm0 = 3.4e38f, rm1 = 3.4e38f, rm2 = 3.4e38f, rm3 = 3.4e38f;

    const unsigned short* aptr = paA + (size_t)(g0 + lc)*16 + lh*8;
    short8_t a = *(const short8_t*)aptr;

    #pragma unroll 2
    for (int gi = 0; gi < NGROUP; ++gi) {
        short8_t an = (gi + 1 < NGROUP)
                      ? *(const short8_t*)(aptr + (size_t)(gi + 1) * 512) : a;
        f32x16 d0, d1, d2, d3;
        asm("v_mfma_f32_32x32x16_bf16 %0, %4, %5, %9\n\t"
            "v_mfma_f32_32x32x16_bf16 %1, %4, %6, %9\n\t"
            "v_mfma_f32_32x32x16_bf16 %2, %4, %7, %9\n\t"
            "v_mfma_f32_32x32x16_bf16 %3, %4, %8, %9\n\t"
            "s_nop 7\n\t"
            "s_nop 7"
            : "=&v"(d0), "=&v"(d1), "=&v"(d2), "=&v"(d3)
            : "v"(a), "v"(Bf[0]), "v"(Bf[1]), "v"(Bf[2]), "v"(Bf[3]), "v"(zc));
        rm0 = tree16c(d0, rm0);
        rm1 = tree16c(d1, rm1);
        rm2 = tree16c(d2, rm2);
        rm3 = tree16c(d3, rm3);
        a = an;
    }

    // merge row-halves (lanes l and l^32: same column, disjoint g-rows)
    rm0 = fminf(rm0, __shfl_xor(rm0, 32, 64));
    rm1 = fminf(rm1, __shfl_xor(rm1, 32, 64));
    rm2 = fminf(rm2, __shfl_xor(rm2, 32, 64));
    rm3 = fminf(rm3, __shfl_xor(rm3, 32, 64));

    if (lh == 0) {
        atomicMin(&keys[pbase + lc],      enc_f32(rm0));
        atomicMin(&keys[pbase + 32 + lc], enc_f32(rm1));
        atomicMin(&keys[pbase + 64 + lc], enc_f32(rm2));
        atomicMin(&keys[pbase + 96 + lc], enc_f32(rm3));
    }
}

// Vector fallback (atomic keys) for small ws.
__global__ __launch_bounds__(256, 4) void k_nn_vec(
        const float4* __restrict__ pws, const float4* __restrict__ gws,
        unsigned* __restrict__ keys) {
    const int tid = threadIdx.x;
    const int pbase = blockIdx.x * 2048;
    const int g0 = blockIdx.y * 64;
    float px[8], py[8], pz[8], sm[8];
    #pragma unroll
    for (int k = 0; k < 8; ++k) {
        float4 p = pws[pbase + k*256 + tid];
        px[k]=p.x; py[k]=p.y; pz[k]=p.z; sm[k]=3.4e38f;
    }
    #pragma unroll 4
    for (int gi = 0; gi < 64; gi += 2) {
        float4 a = gws[g0 + gi];
        float4 b = gws[g0 + gi + 1];
        #pragma unroll
        for (int k = 0; k < 8; ++k) {
            float sa = fmaf(px[k], a.x, fmaf(py[k], a.y, fmaf(pz[k], a.z, a.w)));
            float sb = fmaf(px[k], b.x, fmaf(py[k], b.y, fmaf(pz[k], b.z, b.w)));
            sm[k] = fminf(sm[k], fminf(sa, sb));
        }
    }
    #pragma unroll
    for (int k = 0; k < 8; ++k)
        atomicMin(&keys[pbase + k*256 + tid], enc_f32(sm[k]));
}

// Fin: dis = sqrt(max(pp + dec(key), 0)) (sym) or direct diff; block-reduce
// to psum[block]. No atomics, no fences.
__global__ __launch_bounds__(256) void k_fin(
        const float* __restrict__ R, const float* __restrict__ t,
        const float* __restrict__ m, const float* __restrict__ g,
        const float* __restrict__ ppv, const unsigned* __restrict__ keys,
        const int* __restrict__ midx, float* __restrict__ psum) {
    const int tid = threadIdx.x;
    const int n = blockIdx.x * 256 + tid;
    const bool sym = (midx[0] == 0);
    float dis;
    if (sym) {
        float d2 = ppv[n] + dec_f32(keys[n]);
        dis = sqrtf(fmaxf(d2, 0.f));
    } else {
        float mx=m[3*n+0], my=m[3*n+1], mz=m[3*n+2];
        float dx = fmaf(R[0],mx,fmaf(R[1],my,R[2]*mz)) + t[0] - g[3*n+0];
        float dy = fmaf(R[3],mx,fmaf(R[4],my,R[5]*mz)) + t[1] - g[3*n+1];
        float dz = fmaf(R[6],mx,fmaf(R[7],my,R[8]*mz)) + t[2] - g[3*n+2];
        dis = sqrtf(fmaf(dx,dx,fmaf(dy,dy,dz*dz)));
    }
    #pragma unroll
    for (int off = 32; off > 0; off >>= 1) dis += __shfl_down(dis, off, 64);
    __shared__ float sred[4];
    if ((tid & 63) == 0) sred[tid >> 6] = dis;
    __syncthreads();
    if (tid == 0) psum[blockIdx.x] = (sred[0] + sred[1]) + (sred[2] + sred[3]);
}

// Final: sum psum[NFBLK] -> mean.
__global__ void k_final(const float* __restrict__ psum, float* __restrict__ out) {
    float v = psum[threadIdx.x];
    #pragma unroll
    for (int off = 32; off > 0; off >>= 1) v += __shfl_down(v, off, 64);
    if (threadIdx.x == 0) out[0] = v / (float)N_PTS;
}

extern "C" void kernel_launch(void* const* d_in, const int* in_sizes, int n_in,
                              void* d_out, int out_size, void* d_ws, size_t ws_size,
                              hipStream_t stream) {
    const float* R   = (const float*)d_in[0];
    const float* t   = (const float*)d_in[1];
    const float* m   = (const float*)d_in[2];
    const float* g   = (const float*)d_in[3];
    const int* midx  = (const int*)d_in[4];

    char* ws = (char*)d_ws;
    float* out = (float*)d_out;

    // layout: keys 64K | psum 1K | ppv 64K | pws 256K | gws 256K | paA 512K
    unsigned* keys = (unsigned*)ws;
    float*    psum = (float*)(ws + 65536);
    float*    ppv  = (float*)(ws + 65536 + 1024);
    float4*   pws  = (float4*)(ws + 65536 + 1024 + 65536);
    float4*   gws  = (float4*)(ws + 65536 + 1024 + 65536 + 262144);
    unsigned short* paA = (unsigned short*)(ws + 65536 + 1024 + 65536 + 524288);
    const size_t need = 65536 + 1024 + 65536 + 524288 + 524288;

    if (ws_size >= need) {
        k_prep<false><<<dim3(N_PTS/256), dim3(256), 0, stream>>>(
            R, t, m, g, pws, gws, ppv, paA, keys);
        k_nn_mfma<<<dim3(NPB, NCH), dim3(256), 0, stream>>>(R, t, m, paA, keys);
    } else {
        k_prep<true><<<dim3(N_PTS/256), dim3(256), 0, stream>>>(
            R, t, m, g, pws, gws, ppv, paA, keys);
        k_nn_vec<<<dim3(8, 256), dim3(256), 0, stream>>>(pws, gws, keys);
    }

    k_fin<<<dim3(NFBLK), dim3(256), 0, stream>>>(
        R, t, m, g, ppv, keys, midx, psum);
    k_final<<<dim3(1), dim3(64), 0, stream>>>(psum, out);
}